// Round 1
// baseline (863.866 us; speedup 1.0000x reference)
//
#include <hip/hip_runtime.h>
#include <hip/hip_bf16.h>

// Problem constants
#define BB 4
#define NN 16384
#define EG 131072
#define HH 4
#define DK 32
#define DM 128
#define INVSQ 0.17677669529663687f

typedef unsigned int uint;
typedef unsigned short ushort;

__device__ __forceinline__ float bflo(uint u) { return __uint_as_float(u << 16); }
__device__ __forceinline__ float bfhi(uint u) { return __uint_as_float(u & 0xffff0000u); }
__device__ __forceinline__ ushort f2bf(float f) {
    uint u = __float_as_uint(f);
    u += 0x7fffu + ((u >> 16) & 1u);   // RTNE
    return (ushort)(u >> 16);
}

// Shared tile memory: staging (bf16 W + bf16 X^T) unioned with f32 output tile.
struct __align__(16) SMem {
    union {
        struct {
            ushort sW[128 * 128];     // 32768 B  W[d][c] bf16
            ushort sXt[128][68];      // 17408 B  X^T[d][row] bf16 (pad 68 for b64 align)
        };
        float sY[64][132];            // 33792 B  Y[row][c] f32 (pad 132)
    };
};

// ---- staging helpers (256 threads) ----
__device__ __forceinline__ void stage_w(SMem& sm, const float4* __restrict__ W4, int t) {
#pragma unroll
    for (int i = 0; i < 16; ++i) {
        int f = t + 256 * i;
        float4 w = W4[f];
        ushort4 h;
        h.x = f2bf(w.x); h.y = f2bf(w.y); h.z = f2bf(w.z); h.w = f2bf(w.w);
        *(ushort4*)&sm.sW[4 * f] = h;
    }
}

// stage 64 rows of X (row length 128 f32) transposed into sXt, pairing rows so
// writes are 4B. x transformation applied by caller through raw float4 loads.
__device__ __forceinline__ void stage_xt_rows(SMem& sm, const float4* __restrict__ X4,
                                              size_t r0, int t) {
#pragma unroll
    for (int i = 0; i < 4; ++i) {
        int p = t + 256 * i;           // 1024 pairs
        int e2 = p >> 5;               // 0..31
        int d4 = p & 31;               // float4 index within row
        int e = e2 * 2;
        float4 a = X4[(r0 + e) * 32 + d4];
        float4 b = X4[(r0 + e + 1) * 32 + d4];
        uint u0 = (uint)f2bf(a.x) | ((uint)f2bf(b.x) << 16);
        uint u1 = (uint)f2bf(a.y) | ((uint)f2bf(b.y) << 16);
        uint u2 = (uint)f2bf(a.z) | ((uint)f2bf(b.z) << 16);
        uint u3 = (uint)f2bf(a.w) | ((uint)f2bf(b.w) << 16);
        *(uint*)&sm.sXt[d4 * 4 + 0][e] = u0;
        *(uint*)&sm.sXt[d4 * 4 + 1][e] = u1;
        *(uint*)&sm.sXt[d4 * 4 + 2][e] = u2;
        *(uint*)&sm.sXt[d4 * 4 + 3][e] = u3;
    }
}

// 64x128 tile GEMM core: acc[4 rows][8 cols] per thread, eg=t&15, cg=t>>4
__device__ __forceinline__ void gemm_core(const SMem& sm, int t, float (&acc)[4][8]) {
    int eg = t & 15, cg = t >> 4;
#pragma unroll 2
    for (int d = 0; d < 128; ++d) {
        uint2 ef = *(const uint2*)&sm.sXt[d][eg * 4];
        float xe[4] = { bflo(ef.x), bfhi(ef.x), bflo(ef.y), bfhi(ef.y) };
        uint4 wv = *(const uint4*)&sm.sW[d * 128 + cg * 8];
        float wf[8] = { bflo(wv.x), bfhi(wv.x), bflo(wv.y), bfhi(wv.y),
                        bflo(wv.z), bfhi(wv.z), bflo(wv.w), bfhi(wv.w) };
#pragma unroll
        for (int j = 0; j < 4; ++j)
#pragma unroll
            for (int k = 0; k < 8; ++k)
                acc[j][k] += xe[j] * wf[k];
    }
}

__device__ __forceinline__ void acc_to_sy(SMem& sm, int t, const float (&acc)[4][8]) {
    int eg = t & 15, cg = t >> 4;
#pragma unroll
    for (int j = 0; j < 4; ++j) {
        *(float4*)&sm.sY[eg * 4 + j][cg * 8]     = make_float4(acc[j][0], acc[j][1], acc[j][2], acc[j][3]);
        *(float4*)&sm.sY[eg * 4 + j][cg * 8 + 4] = make_float4(acc[j][4], acc[j][5], acc[j][6], acc[j][7]);
    }
}

// ============================ kernel 1: projection ============================
// Y[r0+0..63][0..127] = X @ W   (rows = B*N), f32 in/out, bf16 internal
__global__ __launch_bounds__(256) void proj128(const float* __restrict__ X,
                                               const float* __restrict__ W,
                                               float* __restrict__ Y) {
    __shared__ SMem sm;
    int t = threadIdx.x;
    size_t r0 = (size_t)blockIdx.x * 64;
    stage_w(sm, (const float4*)W, t);
    stage_xt_rows(sm, (const float4*)X, r0, t);
    __syncthreads();
    float acc[4][8] = {};
    gemm_core(sm, t, acc);
    __syncthreads();
    acc_to_sy(sm, t, acc);
    __syncthreads();
    float4* Y4 = (float4*)Y;
#pragma unroll
    for (int i = 0; i < 8; ++i) {
        int f = t + 256 * i;
        int r = f >> 5, c4 = f & 31;
        Y4[(r0 + r) * 32 + c4] = *(const float4*)&sm.sY[r][c4 * 4];
    }
}

// ============================ kernel 2: edges ============================
// Fused: E = EF @ W_E (64-edge tile), then per-edge scores/exp/scatter.
__global__ __launch_bounds__(256) void edge_kernel(const int* __restrict__ EI,
                                                   const float* __restrict__ EF,
                                                   const float* __restrict__ WE,
                                                   const float* __restrict__ Qp,
                                                   const float* __restrict__ Kp,
                                                   const float* __restrict__ Vp,
                                                   float* __restrict__ num,
                                                   float* __restrict__ den,
                                                   float* __restrict__ attn_out) {
    __shared__ SMem sm;
    __shared__ int sSrc[64];
    __shared__ int sTgt[64];
    int t = threadIdx.x;
    int b = blockIdx.x >> 11;            // 2048 tiles per batch
    int tile = blockIdx.x & 2047;
    int e0 = tile * 64;

    // stage indices
    if (t < 64)        sSrc[t]      = EI[(size_t)b * 2 * EG + e0 + t];
    else if (t < 128)  sTgt[t - 64] = EI[(size_t)b * 2 * EG + EG + e0 + (t - 64)];

    stage_w(sm, (const float4*)WE, t);
    stage_xt_rows(sm, (const float4*)EF, (size_t)b * EG + e0, t);
    __syncthreads();
    float acc[4][8] = {};
    gemm_core(sm, t, acc);
    __syncthreads();
    acc_to_sy(sm, t, acc);      // sY[e][c] = E values
    __syncthreads();

    // phase 3: wave per edge-slice
    int w = t >> 6, lane = t & 63;
    int half = lane >> 5;
    bool isLast = (b == BB - 1);
    for (int ei = 0; ei < 16; ++ei) {
        int e = w * 16 + ei;
        int src = sSrc[e], tgt = sTgt[e];
        const float* qr = Qp + ((size_t)b * NN + src) * 128;
        const float* kr = Kp + ((size_t)b * NN + tgt) * 128;
        const float* vr = Vp + ((size_t)b * NN + tgt) * 128;
        float q0 = qr[lane], q1 = qr[lane + 64];
        float k0 = kr[lane], k1 = kr[lane + 64];
        float v0 = vr[lane], v1 = vr[lane + 64];
        float e0v = sm.sY[e][lane], e1v = sm.sY[e][lane + 64];
        float p0 = q0 * k0 * e0v;
        float p1 = q1 * k1 * e1v;
#pragma unroll
        for (int off = 16; off >= 1; off >>= 1) {
            p0 += __shfl_xor(p0, off, 64);
            p1 += __shfl_xor(p1, off, 64);
        }
        float a0 = __expf(fminf(fmaxf(p0 * INVSQ, -5.f), 5.f));
        float a1 = __expf(fminf(fmaxf(p1 * INVSQ, -5.f), 5.f));
        float* nr = num + ((size_t)b * NN + src) * 128;
        atomicAdd(nr + lane,      a0 * v0);
        atomicAdd(nr + lane + 64, a1 * v1);
        if ((lane & 31) == 0) {
            float* dr = den + ((size_t)b * NN + src) * 4;
            atomicAdd(dr + half,     a0);
            atomicAdd(dr + 2 + half, a1);
            if (isLast) {
                attn_out[(size_t)half * EG + e0 + e]       = a0;
                attn_out[(size_t)(2 + half) * EG + e0 + e] = a1;
            }
        }
    }
}

// ============================ kernel 3: finalize ============================
// x = num/(den+eps); y = x @ W_fc; out = LN(y + input_Q)
__global__ __launch_bounds__(256) void finalize_kernel(const float* __restrict__ num,
                                                       const float* __restrict__ den,
                                                       const float* __restrict__ Wfc,
                                                       const float* __restrict__ IQ,
                                                       const float* __restrict__ G,
                                                       const float* __restrict__ Bt,
                                                       float* __restrict__ Out) {
    __shared__ SMem sm;
    int t = threadIdx.x;
    size_t r0 = (size_t)blockIdx.x * 64;
    stage_w(sm, (const float4*)Wfc, t);
    // stage x = num/(den+eps) transposed
    const float4* N4 = (const float4*)num;
#pragma unroll
    for (int i = 0; i < 4; ++i) {
        int p = t + 256 * i;
        int e2 = p >> 5, d4 = p & 31;
        int e = e2 * 2;
        size_t ra = r0 + e, rb = r0 + e + 1;
        float4 na = N4[ra * 32 + d4];
        float4 nb = N4[rb * 32 + d4];
        int hh = d4 >> 3;  // head of these 4 channels
        float da = den[ra * 4 + hh] + 1e-8f;
        float db = den[rb * 4 + hh] + 1e-8f;
        float ia = 1.f / da, ib = 1.f / db;
        uint u0 = (uint)f2bf(na.x * ia) | ((uint)f2bf(nb.x * ib) << 16);
        uint u1 = (uint)f2bf(na.y * ia) | ((uint)f2bf(nb.y * ib) << 16);
        uint u2 = (uint)f2bf(na.z * ia) | ((uint)f2bf(nb.z * ib) << 16);
        uint u3 = (uint)f2bf(na.w * ia) | ((uint)f2bf(nb.w * ib) << 16);
        *(uint*)&sm.sXt[d4 * 4 + 0][e] = u0;
        *(uint*)&sm.sXt[d4 * 4 + 1][e] = u1;
        *(uint*)&sm.sXt[d4 * 4 + 2][e] = u2;
        *(uint*)&sm.sXt[d4 * 4 + 3][e] = u3;
    }
    __syncthreads();
    float acc[4][8] = {};
    gemm_core(sm, t, acc);
    __syncthreads();
    acc_to_sy(sm, t, acc);
    __syncthreads();

    // epilogue: residual + LN, 16 rows per wave
    int w = t >> 6, lane = t & 63;
    float g0 = G[lane], g1 = G[lane + 64];
    float be0 = Bt[lane], be1 = Bt[lane + 64];
    for (int ei = 0; ei < 16; ++ei) {
        int e = w * 16 + ei;
        size_t row = r0 + e;
        float y0 = sm.sY[e][lane]      + IQ[row * 128 + lane];
        float y1 = sm.sY[e][lane + 64] + IQ[row * 128 + lane + 64];
        float s = y0 + y1;
        float q = y0 * y0 + y1 * y1;
#pragma unroll
        for (int off = 32; off >= 1; off >>= 1) {
            s += __shfl_xor(s, off, 64);
            q += __shfl_xor(q, off, 64);
        }
        float mu = s * (1.f / 128.f);
        float var = q * (1.f / 128.f) - mu * mu;
        float rstd = rsqrtf(var + 1e-5f);
        Out[row * 128 + lane]      = g0 * (y0 - mu) * rstd + be0;
        Out[row * 128 + lane + 64] = g1 * (y1 - mu) * rstd + be1;
    }
}

// ============================ launch ============================
extern "C" void kernel_launch(void* const* d_in, const int* in_sizes, int n_in,
                              void* d_out, int out_size, void* d_ws, size_t ws_size,
                              hipStream_t stream) {
    const int*   EI  = (const int*)d_in[0];
    const float* EF  = (const float*)d_in[1];
    const float* IQ  = (const float*)d_in[2];
    const float* IK  = (const float*)d_in[3];
    const float* IV  = (const float*)d_in[4];
    const float* WQ  = (const float*)d_in[5];
    const float* WK  = (const float*)d_in[6];
    const float* WV  = (const float*)d_in[7];
    const float* WE  = (const float*)d_in[8];
    const float* WFC = (const float*)d_in[9];
    const float* G   = (const float*)d_in[10];
    const float* Bt  = (const float*)d_in[11];

    float* ws = (float*)d_ws;
    const size_t PROJ = (size_t)BB * NN * 128;   // 8,388,608
    float* Qp  = ws;
    float* Kp  = ws + PROJ;
    float* Vp  = ws + 2 * PROJ;
    float* num = ws + 3 * PROJ;
    float* den = ws + 4 * PROJ;                  // B*N*4 floats

    float* out0 = (float*)d_out;
    float* attn_out = out0 + PROJ;               // (1,H,EG,1)

    // zero num+den
    hipMemsetAsync(num, 0, (PROJ + (size_t)BB * NN * 4) * sizeof(float), stream);

    const int projBlocks = (BB * NN) / 64;       // 1024
    proj128<<<projBlocks, 256, 0, stream>>>(IQ, WQ, Qp);
    proj128<<<projBlocks, 256, 0, stream>>>(IK, WK, Kp);
    proj128<<<projBlocks, 256, 0, stream>>>(IV, WV, Vp);

    edge_kernel<<<BB * (EG / 64), 256, 0, stream>>>(EI, EF, WE, Qp, Kp, Vp,
                                                    num, den, attn_out);

    finalize_kernel<<<projBlocks, 256, 0, stream>>>(num, den, WFC, IQ, G, Bt, out0);
}